// Round 5
// baseline (399.655 us; speedup 1.0000x reference)
//
#include <hip/hip_runtime.h>

// Problem constants
#define LL    262144
#define GG    8
#define JJ    8
#define FGF   16
#define WW    31
#define PAD1  15
#define NB    1024           // k positions per block
#define NTHR  512            // 8 waves/block; 4 blocks/CU = 32 waves = 100% slots
#define XTLEN (NB + 32)      // 1056 staged positions: x[nbase-16 .. nbase+NB+15]

typedef __bf16 bf16x8 __attribute__((ext_vector_type(8)));
typedef float  f32x4  __attribute__((ext_vector_type(4)));

__device__ inline unsigned short f2bf(float f) {
    unsigned int u = __float_as_uint(f);
    u = (u + 0x7FFF + ((u >> 16) & 1)) >> 16;   // RNE
    return (unsigned short)u;
}

// Y[16,L] = P[16,256]·XW[256,L] per group (K = 31w x 8j padded to 256).
// MFMA operands: A = X-fragment, B = P-fragment (swapped), so D layout
// (m89-verified: col=lane&15 -> filter, row=q*4+reg -> position) gives each
// lane 4 CONSECUTIVE positions of one filter -> f32x4 coalesced stores.
//
// Occupancy plan (round-3 lesson): measured VGPR=40 -> fits the 64-VGPR
// class -> 8 waves/SIMD legal. LDS 24.7 KB << 40 KB needed for 4 blocks/CU
// of 512 thr. 4 blocks x 8 waves = 32 waves/CU = 100% slots; grid 2048
// blocks = exactly 2 residency rounds (round-3's 1.33 ragged rounds gone).
// Round-2 trauma check: spill shows up as FETCH_SIZE >> 35 MB.
__global__ __launch_bounds__(NTHR, 8)
void conv_mfma(const float* __restrict__ x, const float* __restrict__ p,
               const int* __restrict__ rel, float* __restrict__ out)
{
    __shared__ unsigned short pw[32 * 16 * 8];   // [w][f][j] bf16, w=31 zeroed (8 KB)
    __shared__ unsigned short xt[XTLEN * 8];     // [pos][j]  bf16 (16.5 KB)

    const int t = threadIdx.x;
    const int g = blockIdx.y;
    const long nbase = (long)blockIdx.x * NB;

    // Hoist relation rows (uniform scalar loads).
    const long r0 = rel[g * JJ + 0], r1 = rel[g * JJ + 1];
    const long r2 = rel[g * JJ + 2], r3 = rel[g * JJ + 3];
    const long r4 = rel[g * JJ + 4], r5 = rel[g * JJ + 5];
    const long r6 = rel[g * JJ + 6], r7 = rel[g * JJ + 7];

    // ---- stage x: transpose-in-thread. One POSITION per thread per iter:
    // 8 coalesced scalar dword loads (one per row), one aligned 16B
    // ds_write_b128 (consecutive lanes -> consecutive 16B: conflict-free;
    // measured SQ_LDS_BANK_CONFLICT == 0 with this pattern).
    {
        #pragma unroll
        for (int it = 0; it < (XTLEN + NTHR - 1) / NTHR; ++it) {   // 3 iters
            int c = t + it * NTHR;
            if (c < XTLEN) {
                long gp = nbase - 16 + c;
                unsigned int w0, w1, w2, w3;
                if (gp >= 0 && gp < LL) {
                    float v0 = x[r0 * LL + gp], v1 = x[r1 * LL + gp];
                    float v2 = x[r2 * LL + gp], v3 = x[r3 * LL + gp];
                    float v4 = x[r4 * LL + gp], v5 = x[r5 * LL + gp];
                    float v6 = x[r6 * LL + gp], v7 = x[r7 * LL + gp];
                    w0 = (unsigned int)f2bf(v0) | ((unsigned int)f2bf(v1) << 16);
                    w1 = (unsigned int)f2bf(v2) | ((unsigned int)f2bf(v3) << 16);
                    w2 = (unsigned int)f2bf(v4) | ((unsigned int)f2bf(v5) << 16);
                    w3 = (unsigned int)f2bf(v6) | ((unsigned int)f2bf(v7) << 16);
                } else {
                    w0 = w1 = w2 = w3 = 0u;     // halo outside [0, L)
                }
                uint4 pk; pk.x = w0; pk.y = w1; pk.z = w2; pk.w = w3;
                *(uint4*)&xt[c * 8] = pk;
            }
        }
    }

    // ---- stage P: linear LDS writes, scattered (L2-hot) global reads.
    {
        const float* pg = p + (long)g * FGF * JJ * WW;
        #pragma unroll
        for (int k = 0; k < 8; ++k) {
            int i = t + k * NTHR;            // i = (w*16 + f)*8 + j, 0..4095
            int w = i >> 7;
            int f = (i >> 3) & 15;
            int j = i & 7;
            float v = (w < WW) ? pg[(f * JJ + j) * WW + w] : 0.0f;
            pw[i] = f2bf(v);
        }
    }
    __syncthreads();

    const int lane = t & 63;
    const int wid  = t >> 6;      // wave 0..7, owns positions [wid*128, wid*128+128)
    const int col  = lane & 15;
    const int q    = lane >> 4;   // quad

    // P fragments (B operand): b[s] lane = P[g, f=col, j=0..7, w=s*4+q]
    bf16x8 b[8];
    #pragma unroll
    for (int s = 0; s < 8; ++s)
        b[s] = *(const bf16x8*)&pw[((s * 4 + q) * 16 + col) * 8];

    const int pb = wid * 128 + col + q + 1;   // lane's base xt position

    #define LDX(pos) (*(const bf16x8*)&xt[(pos) * 8])

    // frag(T, s) = LDX(pb + T*16 + s*4); identity frag(T, s+4) == frag(T+1, s)
    bf16x8 F0a = LDX(pb + 0), F0b = LDX(pb + 4), F0c = LDX(pb + 8), F0d = LDX(pb + 12);

    #pragma unroll
    for (int T = 0; T < 8; ++T) {
        const int o = pb + T * 16 + 16;
        bf16x8 F1a = LDX(o + 0), F1b = LDX(o + 4), F1c = LDX(o + 8), F1d = LDX(o + 12);

        f32x4 acc = {0.f, 0.f, 0.f, 0.f};
        acc = __builtin_amdgcn_mfma_f32_16x16x32_bf16(F0a, b[0], acc, 0, 0, 0);
        acc = __builtin_amdgcn_mfma_f32_16x16x32_bf16(F0b, b[1], acc, 0, 0, 0);
        acc = __builtin_amdgcn_mfma_f32_16x16x32_bf16(F0c, b[2], acc, 0, 0, 0);
        acc = __builtin_amdgcn_mfma_f32_16x16x32_bf16(F0d, b[3], acc, 0, 0, 0);
        acc = __builtin_amdgcn_mfma_f32_16x16x32_bf16(F1a, b[4], acc, 0, 0, 0);
        acc = __builtin_amdgcn_mfma_f32_16x16x32_bf16(F1b, b[5], acc, 0, 0, 0);
        acc = __builtin_amdgcn_mfma_f32_16x16x32_bf16(F1c, b[6], acc, 0, 0, 0);
        acc = __builtin_amdgcn_mfma_f32_16x16x32_bf16(F1d, b[7], acc, 0, 0, 0);

        // D layout: lane holds positions (T*16 + q*4 .. +3) of filter `col`.
        const long kc0 = nbase + (long)(wid * 128 + T * 16) + q * 4;
        const size_t ro = (size_t)(g * FGF + col) * LL;
        *(f32x4*)&out[ro + kc0] = acc;

        F0a = F1a; F0b = F1b; F0c = F1c; F0d = F1d;   // roll window
    }
    #undef LDX

    // ---- merged edge fix. Reference TRUNCATES the window at data edges
    // (not zero-pad): overwrite first/last 15 columns in exact fp32.
    // __syncthreads() drains this block's main-loop stores first; only this
    // block writes these columns, so no cross-block ordering is needed.
    if (blockIdx.x == 0 || blockIdx.x == (LL / NB - 1)) {
        __syncthreads();
        if (t < 256) {
            const int f  = t >> 4;
            const int qq = t & 15;
            if (qq < PAD1) {
                const bool left = (blockIdx.x == 0);
                float a = 0.0f;
                for (int j = 0; j < JJ; ++j) {
                    const float* pf = p + (((long)(g * FGF + f)) * JJ + j) * WW;
                    const float* xj = x + (long)rel[g * JJ + j] * LL + (left ? 0 : LL - WW);
                    #pragma unroll
                    for (int w = 0; w < WW; ++w) {
                        // left:  y[qq]      = sum_{w <= qq+15} x[w]      * K[w]
                        // right: y[L-15+qq] = sum_{w >= qq+1 } x[L-31+w] * K[w]
                        bool use = left ? (w <= qq + PAD1) : (w >= qq + 1);
                        if (use) a += xj[w] * pf[w];
                    }
                }
                const size_t ro = (size_t)(g * FGF + f) * LL;
                out[ro + (left ? (long)qq : (long)(LL - PAD1) + qq)] = a;
            }
        }
    }
}

extern "C" void kernel_launch(void* const* d_in, const int* in_sizes, int n_in,
                              void* d_out, int out_size, void* d_ws, size_t ws_size,
                              hipStream_t stream)
{
    const float* x   = (const float*)d_in[0];
    const float* p   = (const float*)d_in[1];
    const int*   rel = (const int*)d_in[2];
    float* out = (float*)d_out;

    dim3 grid(LL / NB, GG);   // (256, 8) = 2048 blocks = 2 exact rounds of 4/CU
    conv_mfma<<<grid, NTHR, 0, stream>>>(x, p, rel, out);
}

// Round 7
// 229.116 us; speedup vs baseline: 1.7443x; 1.7443x over previous
//
#include <hip/hip_runtime.h>

// Problem constants
#define LL    262144
#define GG    8
#define JJ    8
#define FGF   16
#define WW    31
#define PAD1  15
#define NB    512            // positions per tile
#define TILES 4              // tiles per block (persistent, pipelined)
#define NTHR  256            // 4 waves/block
#define XTLEN (NB + 32)      // 544 staged positions per tile
#define NBX   (LL / (NB * TILES))   // 128 blocks per group

typedef __bf16 bf16x8 __attribute__((ext_vector_type(8)));
typedef float  f32x4  __attribute__((ext_vector_type(4)));

__device__ inline unsigned short f2bf(float f) {
    unsigned int u = __float_as_uint(f);
    u = (u + 0x7FFF + ((u >> 16) & 1)) >> 16;   // RNE
    return (unsigned short)u;
}

// Y[16,L] = P[16,256]·XW[256,L] per group (K = 31w x 8j padded to 256).
// A = X-fragment, B = P-fragment (swapped) -> D: col=lane&15 (filter),
// row=q*4+reg (position) -> f32x4 coalesced stores.
//
// Pipelined persistent blocks (T3/T14): per iteration, ISSUE next tile's
// global loads into registers, COMPUTE current tile from LDS buf[cur],
// then pack+ds_write buf[cur^1], one barrier per tile. Global-load latency
// hides under ~700cy of MFMA+ds_read.
//
// Register law (rounds 2+5): this kernel cannot fit the 64-VGPR class --
// LB(...,>=7 waves/EU) => spill => +400MB HBM. LB(256,4) caps at 128.
// Spill tripwire in counters: FETCH_SIZE >> 50 MB.
__global__ __launch_bounds__(NTHR, 4)
void conv_mfma(const float* __restrict__ x, const float* __restrict__ p,
               const int* __restrict__ rel, float* __restrict__ out)
{
    __shared__ unsigned short pw[32 * 16 * 8];     // [w][f][j] bf16, w=31 zeroed (8 KB)
    __shared__ unsigned short xt[2][XTLEN * 8];    // dbuf [pos][j] bf16 (17 KB)

    const int t = threadIdx.x;
    const int g = blockIdx.y;
    const long tbase = (long)blockIdx.x * (NB * TILES);

    // Relation rows (uniform -> SGPRs).
    const long r0 = rel[g * JJ + 0], r1 = rel[g * JJ + 1];
    const long r2 = rel[g * JJ + 2], r3 = rel[g * JJ + 3];
    const long r4 = rel[g * JJ + 4], r5 = rel[g * JJ + 5];
    const long r6 = rel[g * JJ + 6], r7 = rel[g * JJ + 7];

    // Per-thread staged registers for one tile: chunks c = t, t+256, t+512(<32)
    float A[8], B[8], C[8];

    // Issue the 8 row-loads for xt position c of tile with base nb2 (global
    // pos = nb2 - 16 + c). OOB guard only fires in 2 blocks of the grid.
    #define ISSUE(nb2, dst, c)                                              \
        {   long gp = (nb2) - 16 + (c);                                     \
            if (gp >= 0 && gp < LL) {                                       \
                dst[0] = x[r0 * LL + gp]; dst[1] = x[r1 * LL + gp];         \
                dst[2] = x[r2 * LL + gp]; dst[3] = x[r3 * LL + gp];         \
                dst[4] = x[r4 * LL + gp]; dst[5] = x[r5 * LL + gp];         \
                dst[6] = x[r6 * LL + gp]; dst[7] = x[r7 * LL + gp];         \
            } else {                                                        \
                dst[0]=dst[1]=dst[2]=dst[3]=dst[4]=dst[5]=dst[6]=dst[7]=0.f;\
            } }

    #define ISSUE_TILE(nb2)                                                 \
        ISSUE(nb2, A, t);                                                   \
        ISSUE(nb2, B, t + 256);                                             \
        if (t < XTLEN - 512) ISSUE(nb2, C, t + 512);

    // Pack regs -> bf16 transposed LDS. Consecutive lanes -> consecutive
    // 16B ds_write_b128: conflict-free (measured 0 conflicts rounds 3-5).
    #define PACK1(buf, src, c)                                              \
        {   uint4 pk;                                                       \
            pk.x = (unsigned)f2bf(src[0]) | ((unsigned)f2bf(src[1]) << 16); \
            pk.y = (unsigned)f2bf(src[2]) | ((unsigned)f2bf(src[3]) << 16); \
            pk.z = (unsigned)f2bf(src[4]) | ((unsigned)f2bf(src[5]) << 16); \
            pk.w = (unsigned)f2bf(src[6]) | ((unsigned)f2bf(src[7]) << 16); \
            *(uint4*)&xt[buf][(c) * 8] = pk; }

    #define PACK_TILE(buf)                                                  \
        PACK1(buf, A, t);                                                   \
        PACK1(buf, B, t + 256);                                             \
        if (t < XTLEN - 512) PACK1(buf, C, t + 512);

    // ---- prologue: issue tile 0 loads, stage P, load b[], write xt[0]
    ISSUE_TILE(tbase);

    {   // stage P: linear LDS writes, scattered (L2-hot) global reads
        const float* pg = p + (long)g * FGF * JJ * WW;
        #pragma unroll
        for (int k = 0; k < 16; ++k) {
            int i = t + k * NTHR;            // i = (w*16 + f)*8 + j
            int w = i >> 7;
            int f = (i >> 3) & 15;
            int j = i & 7;
            float v = (w < WW) ? pg[(f * JJ + j) * WW + w] : 0.0f;
            pw[i] = f2bf(v);
        }
    }
    __syncthreads();                         // pw visible

    const int lane = t & 63;
    const int wid  = t >> 6;      // wave 0..3, owns positions [wid*128, +128)
    const int col  = lane & 15;
    const int q    = lane >> 4;

    bf16x8 b[8];                             // P frags: b[s] = P[f=col, j=*, w=s*4+q]
    #pragma unroll
    for (int s = 0; s < 8; ++s)
        b[s] = *(const bf16x8*)&pw[((s * 4 + q) * 16 + col) * 8];

    PACK_TILE(0);                            // implicit vmcnt wait on A/B/C
    __syncthreads();                         // xt[0] ready

    const int pb = wid * 128 + col + q + 1;  // lane's base xt position
    #define LDT(buf, pos) (*(const bf16x8*)&xt[buf][(pos) * 8])

    // ---- main pipeline
    #pragma unroll
    for (int i = 0; i < TILES; ++i) {
        const int  cur = i & 1;
        const long nb  = tbase + (long)i * NB;

        if (i + 1 < TILES) { ISSUE_TILE(nb + NB); }    // overlap w/ compute

        // compute tile i from xt[cur]; rolling window
        // frag(T,s) = LDT(cur, pb + T*16 + s*4); frag(T,s+4)==frag(T+1,s)
        bf16x8 F0a = LDT(cur, pb + 0), F0b = LDT(cur, pb + 4),
               F0c = LDT(cur, pb + 8), F0d = LDT(cur, pb + 12);
        #pragma unroll
        for (int T = 0; T < 8; ++T) {
            const int o = pb + T * 16 + 16;
            bf16x8 F1a = LDT(cur, o + 0), F1b = LDT(cur, o + 4),
                   F1c = LDT(cur, o + 8), F1d = LDT(cur, o + 12);

            f32x4 acc = {0.f, 0.f, 0.f, 0.f};
            acc = __builtin_amdgcn_mfma_f32_16x16x32_bf16(F0a, b[0], acc, 0, 0, 0);
            acc = __builtin_amdgcn_mfma_f32_16x16x32_bf16(F0b, b[1], acc, 0, 0, 0);
            acc = __builtin_amdgcn_mfma_f32_16x16x32_bf16(F0c, b[2], acc, 0, 0, 0);
            acc = __builtin_amdgcn_mfma_f32_16x16x32_bf16(F0d, b[3], acc, 0, 0, 0);
            acc = __builtin_amdgcn_mfma_f32_16x16x32_bf16(F1a, b[4], acc, 0, 0, 0);
            acc = __builtin_amdgcn_mfma_f32_16x16x32_bf16(F1b, b[5], acc, 0, 0, 0);
            acc = __builtin_amdgcn_mfma_f32_16x16x32_bf16(F1c, b[6], acc, 0, 0, 0);
            acc = __builtin_amdgcn_mfma_f32_16x16x32_bf16(F1d, b[7], acc, 0, 0, 0);

            // lane holds positions (T*16 + q*4 .. +3) of filter `col`
            const long kc0 = nb + (long)(wid * 128 + T * 16) + q * 4;
            const size_t ro = (size_t)(g * FGF + col) * LL;
            *(f32x4*)&out[ro + kc0] = acc;

            F0a = F1a; F0b = F1b; F0c = F1c; F0d = F1d;
        }

        if (i + 1 < TILES) { PACK_TILE(cur ^ 1); }     // write next buffer
        __syncthreads();   // xt[cur^1] ready; xt[cur] free for overwrite
    }
    #undef LDT

    // ---- merged edge fix. Reference TRUNCATES the window at data edges:
    // overwrite first/last 15 columns in exact fp32. The loop's final
    // __syncthreads() (vmcnt(0)-drained) orders main-loop stores before this.
    if (blockIdx.x == 0 || blockIdx.x == NBX - 1) {
        const int f  = t >> 4;
        const int qq = t & 15;
        if (qq < PAD1) {
            const bool left = (blockIdx.x == 0);
            float a = 0.0f;
            for (int j = 0; j < JJ; ++j) {
                const float* pf = p + (((long)(g * FGF + f)) * JJ + j) * WW;
                const float* xj = x + (long)rel[g * JJ + j] * LL + (left ? 0 : LL - WW);
                #pragma unroll
                for (int w = 0; w < WW; ++w) {
                    // left:  y[qq]      = sum_{w <= qq+15} x[w]      * K[w]
                    // right: y[L-15+qq] = sum_{w >= qq+1 } x[L-31+w] * K[w]
                    bool use = left ? (w <= qq + PAD1) : (w >= qq + 1);
                    if (use) a += xj[w] * pf[w];
                }
            }
            const size_t ro = (size_t)(g * FGF + f) * LL;
            out[ro + (left ? (long)qq : (long)(LL - PAD1) + qq)] = a;
        }
    }
}

extern "C" void kernel_launch(void* const* d_in, const int* in_sizes, int n_in,
                              void* d_out, int out_size, void* d_ws, size_t ws_size,
                              hipStream_t stream)
{
    const float* x   = (const float*)d_in[0];
    const float* p   = (const float*)d_in[1];
    const int*   rel = (const int*)d_in[2];
    float* out = (float*)d_out;

    dim3 grid(NBX, GG);   // (128, 8) = 1024 blocks = 4/CU, single round
    conv_mfma<<<grid, NTHR, 0, stream>>>(x, p, rel, out);
}